// Round 5
// baseline (137.590 us; speedup 1.0000x reference)
//
#include <hip/hip_runtime.h>
#include <hip/hip_bf16.h>

typedef __attribute__((ext_vector_type(8))) short short8;
typedef __attribute__((ext_vector_type(4))) float f32x4;

namespace {
constexpr int Nc  = 2048;   // N
constexpr int NXc = 4096;   // 2N
constexpr int Pc  = 64;
constexpr int Mc  = 4;
constexpr int Dc  = 256;
constexpr int BH  = 16;
constexpr float LOG2E = 1.4426950408889634f;
}

__device__ inline float fexp2(float x) {
#if __has_builtin(__builtin_amdgcn_exp2f)
  return __builtin_amdgcn_exp2f(x);
#else
  return exp2f(x);
#endif
}

__device__ inline unsigned int bfpack(float a, float b) {
  union { __hip_bfloat162 h; unsigned int u; } cv;
  cv.h = __float22bfloat162_rn(make_float2(a, b));
  return cv.u;
}

// Gather-only pre-pass: Wb[bh][m*256+d][64] = bf16( LOG2E * X[bh][SK[b,m,d]][:] )
__global__ __launch_bounds__(256) void prepass_kernel(
    const float* __restrict__ Q, const float* __restrict__ K,
    const int* __restrict__ SK, __hip_bfloat16* __restrict__ Wb)
{
  const int t  = blockIdx.x * 256 + threadIdx.x;
  const int q  = t & 7;
  const int r  = t >> 3;            // 0..16383
  const int bh = r >> 10;
  const int md = r & 1023;
  const int b  = bh >> 3;
  const int idx = SK[b * (Mc * Dc) + md];
  const float* src = (idx < Nc) ? (Q + ((size_t)bh * Nc + idx) * Pc)
                                : (K + ((size_t)bh * Nc + (idx - Nc)) * Pc);
  const f32x4* s4 = (const f32x4*)(src + q * 8);
  f32x4 f0 = s4[0], f1 = s4[1];
  uint4 u;
  u.x = bfpack(f0.x * LOG2E, f0.y * LOG2E);
  u.y = bfpack(f0.z * LOG2E, f0.w * LOG2E);
  u.z = bfpack(f1.x * LOG2E, f1.y * LOG2E);
  u.w = bfpack(f1.z * LOG2E, f1.w * LOG2E);
  *(uint4*)(Wb + (size_t)r * Pc + q * 8) = u;
}

// m-OUTER structure. Register-resident, loop-carried state = X B-fragments
// (b0/b1[8], 64 VGPRs: load + 16-cvt chains the compiler won't rematerialize)
// + acc[8] (32 VGPRs). W A-fragments are deliberately re-read from L2 each m
// (2 x b128 per m, amortized over 8 n-tiles of compute; total W L2 traffic
// 64 MB ~= 2 us aggregate). Zero LDS, zero barriers. Rounds 1-2 failed
// because loop-carried W regs got rematerialized into the hot loop
// (VGPR_Count=64 proved it); here remat of A is the design.
//
// Wave = 16 d x 128 n. Block = 4 waves = 64 d (d-quarter) x 128 n.
// Grid x = 128 = 32 nch * 4 dq, decoded so the 4 dq-siblings (which share an
// X chunk) land on the same XCD's L2: hw round-robins consecutive blockIdx
// across 8 XCDs, so xcd = bx&7, and we give each xcd a contiguous nch range.
//
// MFMA: A = W rows (d), B = X rows (n) => C: row = d (q*4+reg), col = n (brow).
__global__ __launch_bounds__(256, 3) void sketch_main(
    const float* __restrict__ Q, const float* __restrict__ K,
    const __hip_bfloat16* __restrict__ Wb,
    const float* __restrict__ SGN, float* __restrict__ OUT)
{
  const int t    = threadIdx.x;
  const int lane = t & 63;
  const int wv   = t >> 6;
  const int brow = lane & 15;
  const int q    = lane >> 4;
  const int bh   = blockIdx.y;

  // XCD-grouping decode: siblings dq=0..3 of one nch share an XCD
  const int bx  = blockIdx.x;        // 0..127
  const int xcd = bx & 7;
  const int rr  = bx >> 3;           // 0..15
  const int nch = xcd * 4 + (rr >> 2);  // 0..31
  const int dq  = rr & 3;               // 0..3
  const int n0  = nch * 128;
  const int dbase = dq * 64 + wv * 16;  // this wave's 16-d slice

  // --- X -> bf16 B-fragments for all 8 n-tiles (the loop-carried state)
  const float* xbase = ((n0 < Nc) ? (Q + ((size_t)bh * Nc + n0) * Pc)
                                  : (K + ((size_t)bh * Nc + (n0 - Nc)) * Pc))
                       + (size_t)brow * Pc + q * 8;
  short8 b0[8], b1[8];
  #pragma unroll
  for (int it = 0; it < 8; ++it) {
    const float* xp = xbase + (size_t)it * 16 * Pc;
    f32x4 xa = *(const f32x4*)(xp);
    f32x4 xb = *(const f32x4*)(xp + 4);
    f32x4 xc = *(const f32x4*)(xp + 32);
    f32x4 xd = *(const f32x4*)(xp + 36);
    union { short8 s; uint4 u; } c0, c1;
    c0.u.x = bfpack(xa.x, xa.y); c0.u.y = bfpack(xa.z, xa.w);
    c0.u.z = bfpack(xb.x, xb.y); c0.u.w = bfpack(xb.z, xb.w);
    c1.u.x = bfpack(xc.x, xc.y); c1.u.y = bfpack(xc.z, xc.w);
    c1.u.z = bfpack(xd.x, xd.y); c1.u.w = bfpack(xd.z, xd.w);
    b0[it] = c0.s; b1[it] = c1.s;
  }

  f32x4 acc[8];
  #pragma unroll
  for (int it = 0; it < 8; ++it) acc[it] = (f32x4){0.f, 0.f, 0.f, 0.f};

  // --- m-outer loop: A-fragments re-read from L2 each m (cheap by design)
  const __hip_bfloat16* wq =
      Wb + ((size_t)bh * (Mc * Dc) + dbase + brow) * Pc + q * 8;
  #pragma unroll
  for (int m = 0; m < 4; ++m) {
    const __hip_bfloat16* wp = wq + (size_t)m * Dc * Pc;
    short8 a0 = *(const short8*)(wp);
    short8 a1 = *(const short8*)(wp + 32);
    const f32x4 sg = *(const f32x4*)(SGN + m * Dc + dbase + q * 4);
    #pragma unroll
    for (int it = 0; it < 8; ++it) {
      f32x4 c = {0.f, 0.f, 0.f, 0.f};
      c = __builtin_amdgcn_mfma_f32_16x16x32_bf16(a0, b0[it], c, 0, 0, 0);
      c = __builtin_amdgcn_mfma_f32_16x16x32_bf16(a1, b1[it], c, 0, 0, 0);
      acc[it].x = fmaf(sg.x, fexp2(c.x), acc[it].x);
      acc[it].y = fmaf(sg.y, fexp2(c.y), acc[it].y);
      acc[it].z = fmaf(sg.z, fexp2(c.z), acc[it].z);
      acc[it].w = fmaf(sg.w, fexp2(c.w), acc[it].w);
    }
  }

  // --- epilogue: n = n0+it*16+brow (col), d = dbase + q*4 + reg -> one f32x4
  #pragma unroll
  for (int it = 0; it < 8; ++it) {
    float* op = OUT + ((size_t)bh * NXc + n0 + it * 16 + brow) * Dc + dbase + q * 4;
    *(f32x4*)op = acc[it];
  }
}

extern "C" void kernel_launch(void* const* d_in, const int* in_sizes, int n_in,
                              void* d_out, int out_size, void* d_ws, size_t ws_size,
                              hipStream_t stream) {
  (void)in_sizes; (void)n_in; (void)out_size; (void)ws_size;
  const float* Q   = (const float*)d_in[0];
  const float* K   = (const float*)d_in[1];
  const int*   SK  = (const int*)d_in[2];
  const float* SGN = (const float*)d_in[3];
  float* OUT = (float*)d_out;

  __hip_bfloat16* Wb = (__hip_bfloat16*)d_ws;  // 2 MiB

  prepass_kernel<<<dim3(512), dim3(256), 0, stream>>>(Q, K, SK, Wb);
  sketch_main<<<dim3(128, BH), dim3(256), 0, stream>>>(Q, K, Wb, SGN, OUT);
}

// Round 6
// 116.813 us; speedup vs baseline: 1.1779x; 1.1779x over previous
//
#include <hip/hip_runtime.h>
#include <hip/hip_bf16.h>

typedef __attribute__((ext_vector_type(8))) short short8;
typedef __attribute__((ext_vector_type(4))) float f32x4;

namespace {
constexpr int Nc  = 2048;   // N
constexpr int NXc = 4096;   // 2N
constexpr int Pc  = 64;
constexpr int Mc  = 4;
constexpr int Dc  = 256;
constexpr int BH  = 16;
constexpr float LOG2E = 1.4426950408889634f;
}

__device__ inline float fexp2(float x) {
#if __has_builtin(__builtin_amdgcn_exp2f)
  return __builtin_amdgcn_exp2f(x);
#else
  return exp2f(x);
#endif
}

__device__ inline unsigned int bfpack(float a, float b) {
  union { __hip_bfloat162 h; unsigned int u; } cv;
  cv.h = __float22bfloat162_rn(make_float2(a, b));
  return cv.u;
}

// Gather pre-pass: Wb[bh][m*256+d][64] = bf16( LOG2E * X[bh][SK[b,m,d]][:] )
__global__ __launch_bounds__(256) void prepass_kernel(
    const float* __restrict__ Q, const float* __restrict__ K,
    const int* __restrict__ SK, __hip_bfloat16* __restrict__ Wb)
{
  const int t  = blockIdx.x * 256 + threadIdx.x;
  const int q  = t & 7;
  const int r  = t >> 3;            // 0..16383
  const int bh = r >> 10;
  const int md = r & 1023;
  const int b  = bh >> 3;
  const int idx = SK[b * (Mc * Dc) + md];
  const float* src = (idx < Nc) ? (Q + ((size_t)bh * Nc + idx) * Pc)
                                : (K + ((size_t)bh * Nc + (idx - Nc)) * Pc);
  const f32x4* s4 = (const f32x4*)(src + q * 8);
  f32x4 f0 = s4[0], f1 = s4[1];
  uint4 u;
  u.x = bfpack(f0.x * LOG2E, f0.y * LOG2E);
  u.y = bfpack(f0.z * LOG2E, f0.w * LOG2E);
  u.z = bfpack(f1.x * LOG2E, f1.y * LOG2E);
  u.w = bfpack(f1.z * LOG2E, f1.w * LOG2E);
  *(uint4*)(Wb + (size_t)r * Pc + q * 8) = u;
}

// Convert pre-pass: Xb[bh][n][64] = bf16( X[bh][n][:] ), unified Q|K rows.
// Removes ALL fp32->bf16 convert chains from the main kernel, so B-fragments
// become pure 16B loads from an L2/L3-resident 8.4 MB buffer.
__global__ __launch_bounds__(256) void prepass_xb(
    const float* __restrict__ Q, const float* __restrict__ K,
    __hip_bfloat16* __restrict__ Xb)
{
  const int i  = (blockIdx.x * 256 + threadIdx.x) * 8;  // elem index, 8/thread
  const int bh = i >> 18;            // / (4096*64)
  const int row = (i >> 6) & (NXc - 1);
  const int k0 = i & 63;
  const float* src = (row < Nc) ? (Q + ((size_t)bh * Nc + row) * Pc + k0)
                                : (K + ((size_t)bh * Nc + (row - Nc)) * Pc + k0);
  const f32x4* s4 = (const f32x4*)src;
  f32x4 f0 = s4[0], f1 = s4[1];
  uint4 u;
  u.x = bfpack(f0.x, f0.y);
  u.y = bfpack(f0.z, f0.w);
  u.z = bfpack(f1.x, f1.y);
  u.w = bfpack(f1.z, f1.w);
  *(uint4*)(Xb + (size_t)i) = u;
}

// Main: m-OUTER, everything-rematerializable design.
// Loop-carried state that MUST stay resident: acc[8] (32 VGPRs) only.
// b0/b1[8] (64 VGPRs) are pure b128 loads from L2-resident Xb: if the
// allocator keeps them, fine (~115 VGPR peak < 168 cap); if it re-loads
// them per m, that's bounded L2 traffic, NOT scratch. Rounds 1/2/5 died
// because raw-fp32 X (128 VGPRs transient) + cvt chains blew the cap and
// spilled (round 5: WRITE_SIZE 86.6 MB vs 65.5 MB output = 21 MB scratch).
// W A-frags re-read from L2 each m by design. Zero LDS, zero barriers.
//
// Wave = 16 d x 128 n. Block = 4 waves = 64 d (d-quarter) x 128 n.
// Grid x = 128 = 32 nch * 4 dq; decode groups the 4 dq-siblings of one nch
// onto one XCD (hw round-robins blockIdx across 8 XCDs -> xcd = bx&7).
//
// MFMA: A = W rows (d), B = X rows (n) => C: row = d (q*4+reg), col = n (brow).
__global__ __launch_bounds__(256, 3) void sketch_main(
    const __hip_bfloat16* __restrict__ Xb,
    const __hip_bfloat16* __restrict__ Wb,
    const float* __restrict__ SGN, float* __restrict__ OUT)
{
  const int t    = threadIdx.x;
  const int lane = t & 63;
  const int wv   = t >> 6;
  const int brow = lane & 15;
  const int q    = lane >> 4;
  const int bh   = blockIdx.y;

  const int bx  = blockIdx.x;           // 0..127
  const int xcd = bx & 7;
  const int rr  = bx >> 3;              // 0..15
  const int nch = xcd * 4 + (rr >> 2);  // 0..31
  const int dq  = rr & 3;               // 0..3
  const int n0  = nch * 128;
  const int dbase = dq * 64 + wv * 16;  // this wave's 16-d slice

  // --- B-fragments: pure 16B loads (no converts). Lane holds
  //     Xb[bh][n0+it*16+brow][kh*32 + q*8 + j]
  const __hip_bfloat16* xbase =
      Xb + ((size_t)bh * NXc + n0 + brow) * Pc + q * 8;
  short8 b0[8], b1[8];
  #pragma unroll
  for (int it = 0; it < 8; ++it) {
    const __hip_bfloat16* xp = xbase + (size_t)it * 16 * Pc;
    b0[it] = *(const short8*)(xp);
    b1[it] = *(const short8*)(xp + 32);
  }

  f32x4 acc[8];
  #pragma unroll
  for (int it = 0; it < 8; ++it) acc[it] = (f32x4){0.f, 0.f, 0.f, 0.f};

  // --- m-outer loop: A-fragments re-read from L2 each m (cheap by design)
  const __hip_bfloat16* wq =
      Wb + ((size_t)bh * (Mc * Dc) + dbase + brow) * Pc + q * 8;
  #pragma unroll
  for (int m = 0; m < 4; ++m) {
    const __hip_bfloat16* wp = wq + (size_t)m * Dc * Pc;
    short8 a0 = *(const short8*)(wp);
    short8 a1 = *(const short8*)(wp + 32);
    const f32x4 sg = *(const f32x4*)(SGN + m * Dc + dbase + q * 4);
    #pragma unroll
    for (int it = 0; it < 8; ++it) {
      f32x4 c = {0.f, 0.f, 0.f, 0.f};
      c = __builtin_amdgcn_mfma_f32_16x16x32_bf16(a0, b0[it], c, 0, 0, 0);
      c = __builtin_amdgcn_mfma_f32_16x16x32_bf16(a1, b1[it], c, 0, 0, 0);
      acc[it].x = fmaf(sg.x, fexp2(c.x), acc[it].x);
      acc[it].y = fmaf(sg.y, fexp2(c.y), acc[it].y);
      acc[it].z = fmaf(sg.z, fexp2(c.z), acc[it].z);
      acc[it].w = fmaf(sg.w, fexp2(c.w), acc[it].w);
    }
  }

  // --- epilogue: n = n0+it*16+brow (col), d = dbase + q*4 + reg -> one f32x4
  //     (q=0..3 chunks are contiguous 64B per row -> clean coalescing)
  #pragma unroll
  for (int it = 0; it < 8; ++it) {
    float* op = OUT + ((size_t)bh * NXc + n0 + it * 16 + brow) * Dc + dbase + q * 4;
    *(f32x4*)op = acc[it];
  }
}

extern "C" void kernel_launch(void* const* d_in, const int* in_sizes, int n_in,
                              void* d_out, int out_size, void* d_ws, size_t ws_size,
                              hipStream_t stream) {
  (void)in_sizes; (void)n_in; (void)out_size; (void)ws_size;
  const float* Q   = (const float*)d_in[0];
  const float* K   = (const float*)d_in[1];
  const int*   SK  = (const int*)d_in[2];
  const float* SGN = (const float*)d_in[3];
  float* OUT = (float*)d_out;

  __hip_bfloat16* Wb = (__hip_bfloat16*)d_ws;                        // 2 MiB
  __hip_bfloat16* Xb = (__hip_bfloat16*)((char*)d_ws + (4u << 20));  // 8.4 MiB

  prepass_kernel<<<dim3(512), dim3(256), 0, stream>>>(Q, K, SK, Wb);
  prepass_xb<<<dim3(2048), dim3(256), 0, stream>>>(Q, K, Xb);
  sketch_main<<<dim3(128, BH), dim3(256), 0, stream>>>(Xb, Wb, SGN, OUT);
}

// Round 7
// 109.243 us; speedup vs baseline: 1.2595x; 1.0693x over previous
//
#include <hip/hip_runtime.h>
#include <hip/hip_bf16.h>

typedef __attribute__((ext_vector_type(8))) short short8;
typedef __attribute__((ext_vector_type(4))) float f32x4;

namespace {
constexpr int Nc  = 2048;   // N
constexpr int NXc = 4096;   // 2N
constexpr int Pc  = 64;
constexpr int Mc  = 4;
constexpr int Dc  = 256;
constexpr int BH  = 16;
constexpr float LOG2E = 1.4426950408889634f;
}

__device__ inline float fexp2(float x) {
#if __has_builtin(__builtin_amdgcn_exp2f)
  return __builtin_amdgcn_exp2f(x);
#else
  return exp2f(x);
#endif
}

__device__ inline unsigned int bfpack(float a, float b) {
  union { __hip_bfloat162 h; unsigned int u; } cv;
  cv.h = __float22bfloat162_rn(make_float2(a, b));
  return cv.u;
}

// Single fused kernel. Block = (nch, dq, bh): 4 waves, 64 d x 128 n.
//
// Phase 1 (once): gather this block's W slice -- rows X[bh][SK[b, m, dq*64+dl]]
// for m=0..3, dl=0..63 -- scaled by LOG2E, bf16, into a 32 KB LDS tile with
// T2 XOR swizzle (byte ^= (row&7)<<4 per 16B slot) so phase-2 ds_read_b128
// A-frag reads are 2-way (free) instead of 32-way conflicted.
// Phase 2 (after ONE barrier): n-outer loop, NOTHING large loop-carried:
// per n-tile X fp32 load+cvt (16 f32 transient), A from LDS, acc 4 f32 per dt.
// Every operand is cheaply rematerializable -> allocator-proof (rounds 1/2/5
// died from spilled/remat'ed big register arrays; round 6 fixed that but paid
// 2 extra launches + prepass runtimes ~= 25 us. This removes both prepasses.)
//
// Wave wv covers n-tiles {wv*2, wv*2+1} x all 64 d -> block reads its 32 KB
// X chunk exactly once. dq-siblings of one nch are XCD-grouped for L2 reuse.
//
// MFMA: A = W rows (d), B = X rows (n) => C: row = d (q*4+reg), col = n (brow).
__global__ __launch_bounds__(256, 4) void sketch_fused(
    const float* __restrict__ Q, const float* __restrict__ K,
    const int* __restrict__ SK, const float* __restrict__ SGN,
    float* __restrict__ OUT)
{
  __shared__ __hip_bfloat16 Ws[Mc * 64 * Pc];   // 32 KB

  const int t    = threadIdx.x;
  const int lane = t & 63;
  const int wv   = t >> 6;
  const int brow = lane & 15;
  const int q    = lane >> 4;
  const int bh   = blockIdx.y;
  const int b    = bh >> 3;

  // XCD-grouping decode: the 4 dq-siblings of one nch land on one XCD
  const int bx  = blockIdx.x;           // 0..127
  const int xcd = bx & 7;
  const int rr  = bx >> 3;              // 0..15
  const int nch = xcd * 4 + (rr >> 2);  // 0..31
  const int dq  = rr & 3;               // 0..3
  const int n0  = nch * 128;
  const int d0  = dq * 64;

  char* wsb = (char*)Ws;

  // ---- Phase 1: gather W into swizzled LDS. 4 threads per row, 4 m-passes.
  {
    const int dl = t >> 2;              // 0..63 = d within slice
    const int qt = t & 3;               // 16-float quarter of the row
    const int* skp = SK + b * (Mc * Dc) + d0 + dl;
    const int sw = (dl & 7) << 4;
    #pragma unroll
    for (int m = 0; m < 4; ++m) {
      const int idx = skp[m * Dc];
      const float* src = ((idx < Nc) ? (Q + ((size_t)bh * Nc + idx) * Pc)
                                     : (K + ((size_t)bh * Nc + (idx - Nc)) * Pc))
                         + qt * 16;
      f32x4 f0 = *(const f32x4*)(src);
      f32x4 f1 = *(const f32x4*)(src + 4);
      f32x4 f2 = *(const f32x4*)(src + 8);
      f32x4 f3 = *(const f32x4*)(src + 12);
      uint4 ua, ub;
      ua.x = bfpack(f0.x * LOG2E, f0.y * LOG2E);
      ua.y = bfpack(f0.z * LOG2E, f0.w * LOG2E);
      ua.z = bfpack(f1.x * LOG2E, f1.y * LOG2E);
      ua.w = bfpack(f1.z * LOG2E, f1.w * LOG2E);
      ub.x = bfpack(f2.x * LOG2E, f2.y * LOG2E);
      ub.y = bfpack(f2.z * LOG2E, f2.w * LOG2E);
      ub.z = bfpack(f3.x * LOG2E, f3.y * LOG2E);
      ub.w = bfpack(f3.z * LOG2E, f3.w * LOG2E);
      char* rp = wsb + (m * 64 + dl) * 128;
      *(uint4*)(rp + ((qt * 32) ^ sw))      = ua;
      *(uint4*)(rp + ((qt * 32 + 16) ^ sw)) = ub;
    }
  }
  __syncthreads();   // the only barrier in the kernel

  // ---- Phase 2: wave wv -> n-tiles {wv*2, wv*2+1}, all 64 d
  const int swr = (brow & 7) << 4;      // (row&7) == (brow&7): dt*16, m*64 are mult-of-8
  #pragma unroll
  for (int tt = 0; tt < 2; ++tt) {
    const int it = wv * 2 + tt;
    const int nr = n0 + it * 16 + brow;
    const float* xp = ((n0 < Nc) ? (Q + ((size_t)bh * Nc + nr) * Pc)
                                 : (K + ((size_t)bh * Nc + (nr - Nc)) * Pc))
                      + q * 8;
    f32x4 x0 = *(const f32x4*)(xp);
    f32x4 x1 = *(const f32x4*)(xp + 4);
    f32x4 x2 = *(const f32x4*)(xp + 32);
    f32x4 x3 = *(const f32x4*)(xp + 36);
    short8 b0, b1;
    {
      union { short8 s; uint4 u; } c0, c1;
      c0.u.x = bfpack(x0.x, x0.y); c0.u.y = bfpack(x0.z, x0.w);
      c0.u.z = bfpack(x1.x, x1.y); c0.u.w = bfpack(x1.z, x1.w);
      c1.u.x = bfpack(x2.x, x2.y); c1.u.y = bfpack(x2.z, x2.w);
      c1.u.z = bfpack(x3.x, x3.y); c1.u.w = bfpack(x3.z, x3.w);
      b0 = c0.s; b1 = c1.s;
    }

    float* orow = OUT + ((size_t)bh * NXc + nr) * Dc + d0 + q * 4;
    #pragma unroll
    for (int dt = 0; dt < 4; ++dt) {
      f32x4 acc = {0.f, 0.f, 0.f, 0.f};
      #pragma unroll
      for (int m = 0; m < 4; ++m) {
        const char* ap = wsb + (m * 64 + dt * 16 + brow) * 128;
        short8 a0 = *(const short8*)(ap + ((q * 16) ^ swr));
        short8 a1 = *(const short8*)(ap + ((64 + q * 16) ^ swr));
        f32x4 c = {0.f, 0.f, 0.f, 0.f};
        c = __builtin_amdgcn_mfma_f32_16x16x32_bf16(a0, b0, c, 0, 0, 0);
        c = __builtin_amdgcn_mfma_f32_16x16x32_bf16(a1, b1, c, 0, 0, 0);
        const f32x4 sg = *(const f32x4*)(SGN + m * Dc + d0 + dt * 16 + q * 4);
        acc.x = fmaf(sg.x, fexp2(c.x), acc.x);
        acc.y = fmaf(sg.y, fexp2(c.y), acc.y);
        acc.z = fmaf(sg.z, fexp2(c.z), acc.z);
        acc.w = fmaf(sg.w, fexp2(c.w), acc.w);
      }
      // n = nr (col), d = d0 + dt*16 + q*4 + reg -> one f32x4 store
      *(f32x4*)(orow + dt * 16) = acc;
    }
  }
}

extern "C" void kernel_launch(void* const* d_in, const int* in_sizes, int n_in,
                              void* d_out, int out_size, void* d_ws, size_t ws_size,
                              hipStream_t stream) {
  (void)in_sizes; (void)n_in; (void)out_size; (void)d_ws; (void)ws_size;
  const float* Q   = (const float*)d_in[0];
  const float* K   = (const float*)d_in[1];
  const int*   SK  = (const int*)d_in[2];
  const float* SGN = (const float*)d_in[3];
  float* OUT = (float*)d_out;

  sketch_fused<<<dim3(128, BH), dim3(256), 0, stream>>>(Q, K, SK, SGN, OUT);
}

// Round 8
// 104.538 us; speedup vs baseline: 1.3162x; 1.0450x over previous
//
#include <hip/hip_runtime.h>
#include <hip/hip_bf16.h>

typedef __attribute__((ext_vector_type(8))) short short8;
typedef __attribute__((ext_vector_type(4))) float f32x4;

namespace {
constexpr int Nc  = 2048;   // N
constexpr int NXc = 4096;   // 2N
constexpr int Pc  = 64;
constexpr int Mc  = 4;
constexpr int Dc  = 256;
constexpr int BH  = 16;
constexpr float LOG2E = 1.4426950408889634f;
}

__device__ inline float fexp2(float x) {
#if __has_builtin(__builtin_amdgcn_exp2f)
  return __builtin_amdgcn_exp2f(x);
#else
  return exp2f(x);
#endif
}

__device__ inline unsigned int bfpack(float a, float b) {
  union { __hip_bfloat162 h; unsigned int u; } cv;
  cv.h = __float22bfloat162_rn(make_float2(a, b));
  return cv.u;
}

// Single fused kernel, v2. Block = (nch, dq, bh): 4 waves, 64 d x 256 n.
//
// Phase 1 (once): gather W slice (rows X[bh][SK[b, m, dq*64+dl]], m=0..3,
// dl=0..63) scaled by LOG2E into a 32 KB XOR-swizzled LDS tile
// (byte ^= (row&7)<<4 per 16B slot -> uniform bank use on ds_read_b128).
// Phase 2 (after ONE barrier): each wave owns 4 n-tiles. Loop dt->m->tt:
// A-frags ds_read ONCE per (dt,m) and reused across the 4 tiles -> 32
// ds_read_b128/wave covering 4 tiles (round 7: 64 for 2 tiles = 4x the
// LDS traffic per output; LDS was ~10 us/CU of the 43 us kernel).
// exp stays per-m: c is reset per (m,tt), acc[tt] += sg*exp2(c).
// Loop-carried state: b0/b1[4] (32 VGPR) + acc[4] (16) + a (8) ~= 100 VGPR
// -> fits the 128 cap of (256,4); no spill/remat hazard (rounds 1/2/5).
//
// Grid 64 x 16 = 1024 blocks = 4/CU (LDS 128 KB/CU, 16 waves/CU). The 4
// dq-siblings of one nch share an XCD for gather/X L2 reuse (hw round-
// robins blockIdx across 8 XCDs -> xcd = bx&7).
//
// MFMA: A = W rows (d), B = X rows (n) => C: row = d (q*4+reg), col = n (brow).
__global__ __launch_bounds__(256, 4) void sketch_fused(
    const float* __restrict__ Q, const float* __restrict__ K,
    const int* __restrict__ SK, const float* __restrict__ SGN,
    float* __restrict__ OUT)
{
  __shared__ __hip_bfloat16 Ws[Mc * 64 * Pc];   // 32 KB

  const int t    = threadIdx.x;
  const int lane = t & 63;
  const int wv   = t >> 6;
  const int brow = lane & 15;
  const int q    = lane >> 4;
  const int bh   = blockIdx.y;
  const int b    = bh >> 3;

  // XCD-grouping decode: 4 dq-siblings of one nch on one XCD
  const int bx  = blockIdx.x;           // 0..63
  const int xcd = bx & 7;
  const int rr  = bx >> 3;              // 0..7
  const int nch = xcd * 2 + (rr >> 2);  // 0..15
  const int dq  = rr & 3;               // 0..3
  const int n0  = nch * 256;
  const int d0  = dq * 64;

  char* wsb = (char*)Ws;

  // ---- Phase 1: gather W into swizzled LDS. 4 threads per row, 4 m-passes.
  {
    const int dl = t >> 2;              // 0..63 = d within slice
    const int qt = t & 3;               // 16-float quarter of the row
    const int* skp = SK + b * (Mc * Dc) + d0 + dl;
    const int sw = (dl & 7) << 4;
    #pragma unroll
    for (int m = 0; m < 4; ++m) {
      const int idx = skp[m * Dc];
      const float* src = ((idx < Nc) ? (Q + ((size_t)bh * Nc + idx) * Pc)
                                     : (K + ((size_t)bh * Nc + (idx - Nc)) * Pc))
                         + qt * 16;
      f32x4 f0 = *(const f32x4*)(src);
      f32x4 f1 = *(const f32x4*)(src + 4);
      f32x4 f2 = *(const f32x4*)(src + 8);
      f32x4 f3 = *(const f32x4*)(src + 12);
      uint4 ua, ub;
      ua.x = bfpack(f0.x * LOG2E, f0.y * LOG2E);
      ua.y = bfpack(f0.z * LOG2E, f0.w * LOG2E);
      ua.z = bfpack(f1.x * LOG2E, f1.y * LOG2E);
      ua.w = bfpack(f1.z * LOG2E, f1.w * LOG2E);
      ub.x = bfpack(f2.x * LOG2E, f2.y * LOG2E);
      ub.y = bfpack(f2.z * LOG2E, f2.w * LOG2E);
      ub.z = bfpack(f3.x * LOG2E, f3.y * LOG2E);
      ub.w = bfpack(f3.z * LOG2E, f3.w * LOG2E);
      char* rp = wsb + (m * 64 + dl) * 128;
      *(uint4*)(rp + ((qt * 32) ^ sw))      = ua;
      *(uint4*)(rp + ((qt * 32 + 16) ^ sw)) = ub;
    }
  }
  __syncthreads();   // the only barrier in the kernel

  // ---- Phase 2: wave wv -> n-tiles {wv*4 .. wv*4+3}, all 64 d
  // B-fragments for the wave's 4 tiles (loop-carried, ~32 VGPR)
  const float* xr = ((n0 < Nc) ? (Q + ((size_t)bh * Nc + n0) * Pc)
                               : (K + ((size_t)bh * Nc + (n0 - Nc)) * Pc))
                    + (size_t)(wv * 64 + brow) * Pc + q * 8;
  short8 b0[4], b1[4];
  #pragma unroll
  for (int tt = 0; tt < 4; ++tt) {
    const float* xp = xr + (size_t)tt * 16 * Pc;
    f32x4 x0 = *(const f32x4*)(xp);
    f32x4 x1 = *(const f32x4*)(xp + 4);
    f32x4 x2 = *(const f32x4*)(xp + 32);
    f32x4 x3 = *(const f32x4*)(xp + 36);
    union { short8 s; uint4 u; } c0, c1;
    c0.u.x = bfpack(x0.x, x0.y); c0.u.y = bfpack(x0.z, x0.w);
    c0.u.z = bfpack(x1.x, x1.y); c0.u.w = bfpack(x1.z, x1.w);
    c1.u.x = bfpack(x2.x, x2.y); c1.u.y = bfpack(x2.z, x2.w);
    c1.u.z = bfpack(x3.x, x3.y); c1.u.w = bfpack(x3.z, x3.w);
    b0[tt] = c0.s; b1[tt] = c1.s;
  }

  const int swr = (brow & 7) << 4;   // row&7 == brow&7 (dt*16, m*64 mult of 8)
  float* obase = OUT + ((size_t)bh * NXc + n0 + wv * 64 + brow) * Dc + d0 + q * 4;

  #pragma unroll
  for (int dt = 0; dt < 4; ++dt) {
    f32x4 acc[4];
    #pragma unroll
    for (int tt = 0; tt < 4; ++tt) acc[tt] = (f32x4){0.f, 0.f, 0.f, 0.f};

    #pragma unroll
    for (int m = 0; m < 4; ++m) {
      const char* ap = wsb + (m * 64 + dt * 16 + brow) * 128;
      short8 a0 = *(const short8*)(ap + ((q * 16) ^ swr));
      short8 a1 = *(const short8*)(ap + ((64 + q * 16) ^ swr));
      const f32x4 sg = *(const f32x4*)(SGN + m * Dc + d0 + dt * 16 + q * 4);
      #pragma unroll
      for (int tt = 0; tt < 4; ++tt) {
        f32x4 c = {0.f, 0.f, 0.f, 0.f};
        c = __builtin_amdgcn_mfma_f32_16x16x32_bf16(a0, b0[tt], c, 0, 0, 0);
        c = __builtin_amdgcn_mfma_f32_16x16x32_bf16(a1, b1[tt], c, 0, 0, 0);
        acc[tt].x = fmaf(sg.x, fexp2(c.x), acc[tt].x);
        acc[tt].y = fmaf(sg.y, fexp2(c.y), acc[tt].y);
        acc[tt].z = fmaf(sg.z, fexp2(c.z), acc[tt].z);
        acc[tt].w = fmaf(sg.w, fexp2(c.w), acc[tt].w);
      }
    }

    // n = n0 + (wv*4+tt)*16 + brow (col), d = d0 + dt*16 + q*4 + reg
    #pragma unroll
    for (int tt = 0; tt < 4; ++tt) {
      *(f32x4*)(obase + (size_t)tt * 16 * Dc + dt * 16) = acc[tt];
    }
  }
}

extern "C" void kernel_launch(void* const* d_in, const int* in_sizes, int n_in,
                              void* d_out, int out_size, void* d_ws, size_t ws_size,
                              hipStream_t stream) {
  (void)in_sizes; (void)n_in; (void)out_size; (void)d_ws; (void)ws_size;
  const float* Q   = (const float*)d_in[0];
  const float* K   = (const float*)d_in[1];
  const int*   SK  = (const int*)d_in[2];
  const float* SGN = (const float*)d_in[3];
  float* OUT = (float*)d_out;

  sketch_fused<<<dim3(64, BH), dim3(256), 0, stream>>>(Q, K, SK, SGN, OUT);
}